// Round 22
// baseline (848.367 us; speedup 1.0000x reference)
//
#include <hip/hip_runtime.h>
#include <hip/hip_bf16.h>

#define DM 512      // d_model
#define DI 1024     // d_inner
#define DSTATE 16
#define DTR 32      // dt_rank
#define NLAYER 8
#define BS 4
#define LL 256      // tokens per batch (F*NP)
#define MT 1024     // BS*LL total tokens
#define DPROJ 256
#define CL 32       // scan chunk length
#define NCH (LL/CL)

typedef unsigned short u16;
typedef unsigned int u32;
typedef __attribute__((ext_vector_type(8))) short short8;
typedef __attribute__((ext_vector_type(4))) float f32x4;

__device__ __forceinline__ float sigmoidf_(float x){ return 1.f/(1.f+__expf(-x)); }

// fp32 -> bf16 round-to-nearest-even (finite inputs)
__device__ __forceinline__ u16 f2bf(float f){
  unsigned u = __float_as_uint(f);
  u = (u + 0x7FFF + ((u>>16)&1)) >> 16;
  return (u16)u;
}
__device__ __forceinline__ float bf2f(u16 v){
  return __uint_as_float(((unsigned)v) << 16);
}

// VALU-pipe 16-lane sum via DPP row rotations
template<int CTRL>
__device__ __forceinline__ float dpp_ror_add(float x){
  int y = __builtin_amdgcn_update_dpp(0, __float_as_int(x), CTRL, 0xF, 0xF, false);
  return x + __int_as_float(y);
}
__device__ __forceinline__ float sum16_dpp(float x){
  x = dpp_ror_add<0x128>(x);
  x = dpp_ror_add<0x124>(x);
  x = dpp_ror_add<0x122>(x);
  x = dpp_ror_add<0x121>(x);
  return x;
}

// ---------------- patch embed
__global__ __launch_bounds__(256) void embed_k(const float* __restrict__ ts,
    const float* __restrict__ ew, const float* __restrict__ eb, float* __restrict__ x){
  int idx = blockIdx.x*256 + threadIdx.x;     // MT*DM
  int m = idx >> 9, d = idx & 511;
  int b = m >> 8, np_ = m & 255;
  const float* t0 = ts + b*1024 + np_*4;
  float acc = eb[d];
  #pragma unroll
  for (int p=0;p<4;p++) acc = fmaf(t0[p], ew[d*4+p], acc);
  x[idx] = acc;
}

// ---------------- cast ALL weights to bf16; 2 coalesced float4 streams/thread
#define WHALF 3342336
__global__ __launch_bounds__(256) void wcastall_k(
    const float* __restrict__ w_in, const float* __restrict__ w_out,
    const float* __restrict__ w_xp, const float* __restrict__ w_pj,
    u16* __restrict__ dst){
  int t = blockIdx.x*256 + threadIdx.x;   // WHALF threads
  #pragma unroll
  for (int hh=0; hh<2; ++hh){
    long e4 = ((long)t + (long)hh*WHALF)*4;
    const float* src; long o;
    if      (e4 < 16777216) { src = w_in;  o = e4; }
    else if (e4 < 25165824) { src = w_out; o = e4 - 16777216; }
    else if (e4 < 26214400) { src = w_xp;  o = e4 - 25165824; }
    else                    { src = w_pj;  o = e4 - 26214400; }
    float4 v = *(const float4*)(src + o);
    ushort4 r; r.x=f2bf(v.x); r.y=f2bf(v.y); r.z=f2bf(v.z); r.w=f2bf(v.w);
    *(ushort4*)(dst + e4) = r;
  }
}

// ---------------- fused (residual combine) + rmsnorm -> bf16 normal+flipped
__global__ __launch_bounds__(256) void rmscomb_k(float* __restrict__ x,
    const float* __restrict__ yout,   // nullptr for layer 0
    const float* __restrict__ nw, u16* __restrict__ xnbf, u16* __restrict__ xnfbf){
  int m = blockIdx.x, t = threadIdx.x;
  int b = m>>8, l = m&255, mf = (b<<8)+(255-l);
  float2 v = *(const float2*)&x[(long)m*DM + t*2];
  if (yout){
    float2 f = *(const float2*)&yout[(long)m*DM + t*2];
    float2 g = *(const float2*)&yout[(long)MT*DM + (long)mf*DM + t*2];
    v.x += f.x + g.x; v.y += f.y + g.y;
    *(float2*)&x[(long)m*DM + t*2] = v;
  }
  float ss = v.x*v.x + v.y*v.y;
  ss += __shfl_down(ss,32); ss += __shfl_down(ss,16); ss += __shfl_down(ss,8);
  ss += __shfl_down(ss,4);  ss += __shfl_down(ss,2);  ss += __shfl_down(ss,1);
  __shared__ float ps[4];
  if ((t&63)==0) ps[t>>6] = ss;
  __syncthreads();
  float tot = ps[0]+ps[1]+ps[2]+ps[3];
  float rs = rsqrtf(tot*(1.f/DM) + 1e-5f);
  ushort2 o; o.x = f2bf(v.x*rs*nw[t*2]); o.y = f2bf(v.y*rs*nw[t*2+1]);
  *(ushort2*)&xnbf [(long)m *DM + t*2] = o;
  *(ushort2*)&xnfbf[(long)mf*DM + t*2] = o;
}

// ---------------- final combine + cast to bf16
__global__ __launch_bounds__(256) void combcast_k(const float* __restrict__ x,
    const float* __restrict__ yout, u16* __restrict__ xbf){
  int idx = blockIdx.x*256 + threadIdx.x;   // MT*DM/4
  int m = idx >> 7, c4 = idx & 127;
  int b = m>>8, l = m&255, mf = (b<<8)+(255-l);
  float4 r = ((const float4*)x)[idx];
  float4 f = ((const float4*)yout)[idx];
  float4 g = ((const float4*)(yout + (long)MT*DM))[(long)mf*128 + c4];
  ushort4 o;
  o.x = f2bf(r.x + f.x + g.x); o.y = f2bf(r.y + f.y + g.y);
  o.z = f2bf(r.z + f.z + g.z); o.w = f2bf(r.w + f.w + g.w);
  ((ushort4*)xbf)[idx] = o;
}

// ---------------- bf16 MFMA GEMM: C = A @ W^T (both bf16, global_load_lds staging)
// SPLITK>1: z = dir*SPLITK+kc, fp32 partials at C + z*M*N.
// EPI: 0 plain | 2 final scatter+bias | 4 in_proj split: n<1024 -> fp32 C, else silu bf16 -> G
template<int BM,int BN,int SPLITK,int EPI>
__global__ __launch_bounds__(256) void mfma_nt(
    const u16* __restrict__ A, int lda, long sA,
    const u16* __restrict__ W, int ldw, long sW,
    const float* __restrict__ bias, u16* __restrict__ G,
    float* __restrict__ C, int ldc, long sC,
    int M, int N, int K)
{
  constexpr int WM = BM/2, WN = BN/2;
  constexpr int MI = WM/16, NI = WN/16;
  int z = blockIdx.z;
  int dir = z / SPLITK, kc = z % SPLITK;
  int Klen = K / SPLITK;
  int kbase = kc * Klen;
  A += (long)dir * sA;
  W += (long)dir * sW;
  if (SPLITK > 1) C += (long)z * M * N; else C += (long)dir * sC;
  if (EPI==4) G += (long)dir * (long)MT*DI;

  __shared__ u16 Al[BM*32];
  __shared__ u16 Wl[BN*32];
  int tid = threadIdx.x;
  int lane = tid & 63;
  int wave = tid >> 6;
  int wm0 = (wave>>1)*WM, wn0 = (wave&1)*WN;
  int m0 = blockIdx.y*BM, n0 = blockIdx.x*BN;
  int l16 = lane>>4, l15 = lane&15;

  f32x4 acc[MI][NI] = {};

  for (int k0=0; k0<Klen; k0+=32){
    #pragma unroll
    for (int it=0; it<BM*4/256; ++it){
      int ch = it*256 + tid;
      int row = ch % BM, kk = ch / BM;
      const u16* g = A + (long)(m0+row)*lda + kbase + k0 + kk*8;
      __builtin_amdgcn_global_load_lds(
          (const __attribute__((address_space(1))) void*)g,
          (__attribute__((address_space(3))) void*)(Al + ch*8), 16, 0, 0);
    }
    #pragma unroll
    for (int it=0; it<BN*4/256; ++it){
      int ch = it*256 + tid;
      int row = ch % BN, kk = ch / BN;
      const u16* g = W + (long)(n0+row)*ldw + kbase + k0 + kk*8;
      __builtin_amdgcn_global_load_lds(
          (const __attribute__((address_space(1))) void*)g,
          (__attribute__((address_space(3))) void*)(Wl + ch*8), 16, 0, 0);
    }
    __syncthreads();
    short8 a[MI], b[NI];
    #pragma unroll
    for (int i=0;i<MI;i++)
      a[i] = *(const short8*)&Al[(l16*BM + wm0 + i*16 + l15)*8];
    #pragma unroll
    for (int j=0;j<NI;j++)
      b[j] = *(const short8*)&Wl[(l16*BN + wn0 + j*16 + l15)*8];
    #pragma unroll
    for (int i=0;i<MI;i++)
      #pragma unroll
      for (int j=0;j<NI;j++)
        acc[i][j] = __builtin_amdgcn_mfma_f32_16x16x32_bf16(a[i], b[j], acc[i][j], 0,0,0);
    __syncthreads();
  }
  #pragma unroll
  for (int i=0;i<MI;i++){
    #pragma unroll
    for (int j=0;j<NI;j++){
      #pragma unroll
      for (int r=0;r<4;r++){
        int m = m0 + wm0 + i*16 + l16*4 + r;
        int n = n0 + wn0 + j*16 + l15;
        float v = acc[i][j][r];
        if (EPI==2){
          v += bias[n];
          int bb = m>>8, np_ = m&255, p = n>>8, dp = n&255;
          C[((long)(bb*1024 + np_*4 + p))*256 + dp] = v;
        } else if (EPI==4){
          if (n < 1024) C[(long)m*1024 + n] = v;
          else          G[(long)m*1024 + (n-1024)] = f2bf(v * sigmoidf_(v));
        } else {
          C[(long)m*ldc + n] = v;
        }
      }
    }
  }
}

// ---------------- split-K reduce for xproj
__global__ __launch_bounds__(256) void xreduce_k(const float* __restrict__ part,
    float* __restrict__ xdbl){
  int idx = blockIdx.x*256 + threadIdx.x;   // 131072
  int d = idx >> 16, off = idx & 65535;
  float s = 0.f;
  #pragma unroll
  for (int kc=0; kc<8; ++kc) s += part[((d*8+kc)<<16) + off];
  xdbl[idx] = s;
}

// ---------------- causal depthwise conv + bias + silu -> bf16 u (vectorized 4e x 4l)
__global__ __launch_bounds__(256) void conv_silu_k(const float* __restrict__ xzu,
    const float* __restrict__ cw, const float* __restrict__ cb,
    u16* __restrict__ ubf){
  int idx = blockIdx.x*256 + threadIdx.x;   // 131072
  int e = (idx & 255) * 4;
  int grp = idx >> 8;          // 512: dir(1) | b(2) | lg(6)
  int dir = grp >> 8;
  int b   = (grp >> 6) & 3;
  int l0  = (grp & 63) * 4;
  long dm0 = (long)dir*MT + b*LL + l0;
  const float* w = cw + ((long)dir*DI + e)*4;
  float4 w0 = *(const float4*)&w[0];
  float4 w1 = *(const float4*)&w[4];
  float4 w2 = *(const float4*)&w[8];
  float4 w3 = *(const float4*)&w[12];
  float4 bias = *(const float4*)&cb[dir*DI + e];
  const float* src = xzu + dm0*DI + e;
  float4 vb[7];
  #pragma unroll
  for (int j=0;j<7;j++){
    int l = l0 - 3 + j;
    if (l >= 0) vb[j] = *(const float4*)&src[(long)(j-3)*DI];
    else        vb[j] = make_float4(0.f,0.f,0.f,0.f);
  }
  #pragma unroll
  for (int j=0;j<4;j++){
    float4 acc = bias;
    acc.x = fmaf(w0.x, vb[j].x,   acc.x); acc.x = fmaf(w0.y, vb[j+1].x, acc.x);
    acc.x = fmaf(w0.z, vb[j+2].x, acc.x); acc.x = fmaf(w0.w, vb[j+3].x, acc.x);
    acc.y = fmaf(w1.x, vb[j].y,   acc.y); acc.y = fmaf(w1.y, vb[j+1].y, acc.y);
    acc.y = fmaf(w1.z, vb[j+2].y, acc.y); acc.y = fmaf(w1.w, vb[j+3].y, acc.y);
    acc.z = fmaf(w2.x, vb[j].z,   acc.z); acc.z = fmaf(w2.y, vb[j+1].z, acc.z);
    acc.z = fmaf(w2.z, vb[j+2].z, acc.z); acc.z = fmaf(w2.w, vb[j+3].z, acc.z);
    acc.w = fmaf(w3.x, vb[j].w,   acc.w); acc.w = fmaf(w3.y, vb[j+1].w, acc.w);
    acc.w = fmaf(w3.z, vb[j+2].w, acc.w); acc.w = fmaf(w3.w, vb[j+3].w, acc.w);
    float vx = acc.x * sigmoidf_(acc.x);
    float vy = acc.y * sigmoidf_(acc.y);
    float vz = acc.z * sigmoidf_(acc.z);
    float vw = acc.w * sigmoidf_(acc.w);
    ushort4 o; o.x=f2bf(vx); o.y=f2bf(vy); o.z=f2bf(vz); o.w=f2bf(vw);
    *(ushort4*)&ubf[(dm0+j)*DI + e] = o;
  }
}

// ---------------- selective scan: R21 structure + delta-input reg prefetch
// + redundant barrier removed (2 barriers/chunk)
__global__ __launch_bounds__(256) void scan_k(
    const u16* __restrict__ ubf, const u16* __restrict__ gbf,
    const float* __restrict__ xdbl, const float* __restrict__ dtw,
    const float* __restrict__ dtb, const float* __restrict__ A_log,
    const float* __restrict__ Dp, u16* __restrict__ ygbf)
{
  int t = threadIdx.x;
  int n = t & 15, el = t >> 4;
  int id = blockIdx.x + 64*blockIdx.y + 256*blockIdx.z;   // 0..511
  int xcd = id & 7, slot = id >> 3;
  int ec = xcd*8 + (slot & 7);
  int bd = slot >> 3;
  int b = bd & 3, dir = bd >> 2;

  int e0 = ec*16, e = e0 + el;
  float Av = -__expf(A_log[((long)dir*DI + e)*16 + n]);
  float Dv = Dp[dir*DI + e];
  long mbase = (long)dir*MT + b*LL;
  const u16* up_ = ubf + mbase*DI;
  const u16* gp_ = gbf + mbase*DI;
  const float* xd_ = xdbl + mbase*64;
  u16* yp_ = ygbf + mbase*DI;

  float wrow[32];
  {
    const float* wr = dtw + ((long)dir*DI + e0 + n)*32;
    #pragma unroll
    for (int r4=0;r4<8;r4++) *(float4*)&wrow[r4*4] = *(const float4*)&wr[r4*4];
  }
  float dtbv = dtb[dir*DI + e0 + n];

  __shared__ float sDU[2][16][68];   // [el][l*2 + {0:d,1:u}]
  __shared__ float sBC[2][16][68];   // [n][l*2 + {0:B,1:C}]
  __shared__ float sy [32][20];

  float4 xbc; ushort4 uvv;
  float4 dreg[2][8];                 // delta-input rows (this thread's 2 rows)
  auto load_pre = [&](int c){
    long l0 = (long)c*CL;
    int row = t >> 3, c4 = (t & 7)*4;     // 32 rows x 8 float4 (cols 32..63)
    xbc = *(const float4*)&xd_[(l0 + row)*64 + 32 + c4];
    if (t < 128) uvv = *(const ushort4*)&up_[(l0 + (t>>2))*DI + e0 + (t&3)*4];
  };
  auto write_pre = [&](int buf){
    int row = t >> 3, c4 = (t & 7)*4;
    if (c4 < 16){
      int nb = c4;
      sBC[buf][nb  ][row*2] = xbc.x; sBC[buf][nb+1][row*2] = xbc.y;
      sBC[buf][nb+2][row*2] = xbc.z; sBC[buf][nb+3][row*2] = xbc.w;
    } else {
      int nb = c4 - 16;
      sBC[buf][nb  ][row*2+1] = xbc.x; sBC[buf][nb+1][row*2+1] = xbc.y;
      sBC[buf][nb+2][row*2+1] = xbc.z; sBC[buf][nb+3][row*2+1] = xbc.w;
    }
    if (t < 128){
      int l = t>>2, e4 = (t&3)*4;
      sDU[buf][e4  ][l*2+1] = bf2f(uvv.x);
      sDU[buf][e4+1][l*2+1] = bf2f(uvv.y);
      sDU[buf][e4+2][l*2+1] = bf2f(uvv.z);
      sDU[buf][e4+3][l*2+1] = bf2f(uvv.w);
    }
  };
  auto dload = [&](int c){
    #pragma unroll
    for (int j=0;j<2;j++){
      const float* row = &xd_[((long)c*CL + el + j*16)*64];
      #pragma unroll
      for (int r4=0;r4<8;r4++) dreg[j][r4] = *(const float4*)&row[r4*4];
    }
  };

  load_pre(0);
  write_pre(0);
  load_pre(1);
  dload(0);
  __syncthreads();

  float h = 0.f;
  for (int c = 0; c < NCH; ++c){
    int cur = c & 1;
    // delta: pure VALU from prefetched dreg; writes d-slots of sDU[cur]
    #pragma unroll
    for (int j=0;j<2;j++){
      int l = el + j*16;
      float acc = dtbv;
      #pragma unroll
      for (int r4=0;r4<8;r4++){
        float4 d4 = dreg[j][r4];
        acc = fmaf(d4.x, wrow[r4*4],   acc);
        acc = fmaf(d4.y, wrow[r4*4+1], acc);
        acc = fmaf(d4.z, wrow[r4*4+2], acc);
        acc = fmaf(d4.w, wrow[r4*4+3], acc);
      }
      acc = fmaxf(acc, 0.f) + __logf(1.f + __expf(-fabsf(acc)));
      sDU[cur][n][l*2] = acc;
    }
    ushort4 gv;
    if (t < 128) gv = *(const ushort4*)&gp_[((long)c*CL + (t>>2))*DI + e0 + (t&3)*4];
    __syncthreads();   // #1: d-slots + staged buffers visible

    if (c+1 < NCH) dload(c+1);   // issue next chunk's delta loads under compute

    const float* pDU = &sDU[cur][el][0];
    const float* pBC = &sBC[cur][n][0];
    float4 duv[16], bcv[16];
    #pragma unroll
    for (int l2=0; l2<16; ++l2){
      duv[l2] = *(const float4*)&pDU[l2*4];
      bcv[l2] = *(const float4*)&pBC[l2*4];
    }
    float dA[32], sv[32], cv[32], ud[32];
    #pragma unroll
    for (int l2=0; l2<16; ++l2){
      dA[2*l2]   = __expf(duv[l2].x*Av);
      sv[2*l2]   = duv[l2].x*duv[l2].y*bcv[l2].x;
      cv[2*l2]   = bcv[l2].y;
      ud[2*l2]   = duv[l2].y*Dv;
      dA[2*l2+1] = __expf(duv[l2].z*Av);
      sv[2*l2+1] = duv[l2].z*duv[l2].w*bcv[l2].z;
      cv[2*l2+1] = bcv[l2].w;
      ud[2*l2+1] = duv[l2].w*Dv;
    }
    #pragma unroll
    for (int l=0; l<32; ++l){
      h = fmaf(dA[l], h, sv[l]);
      sv[l] = h;
    }
    #pragma unroll
    for (int l=0; l<32; ++l) sv[l] = sum16_dpp(sv[l]*cv[l]);
    if (n==0){
      #pragma unroll
      for (int l=0; l<32; ++l) sy[l][el] = sv[l] + ud[l];
    }
    __syncthreads();   // #2: sy complete; buffers[cur] free
    if (c+1 < NCH){
      write_pre(cur^1);
      if (c+2 < NCH) load_pre(c+2);
    }
    if (t < 128){
      float4 y4 = *(const float4*)&sy[t>>2][(t&3)*4];
      ushort4 o;
      o.x = f2bf(y4.x * bf2f(gv.x)); o.y = f2bf(y4.y * bf2f(gv.y));
      o.z = f2bf(y4.z * bf2f(gv.z)); o.w = f2bf(y4.w * bf2f(gv.w));
      *(ushort4*)&yp_[((long)c*CL + (t>>2))*DI + e0 + (t&3)*4] = o;
    }
    // no 3rd barrier: next iter's barrier #1 orders sy/LDS hazards
  }
}

extern "C" void kernel_launch(void* const* d_in, const int* in_sizes, int n_in,
                              void* d_out, int out_size, void* d_ws, size_t ws_size,
                              hipStream_t stream){
  const float* ts   = (const float*)d_in[0];
  const float* ew   = (const float*)d_in[2];
  const float* eb   = (const float*)d_in[3];
  const float* nw   = (const float*)d_in[4];
  const float* inw  = (const float*)d_in[5];
  const float* cw   = (const float*)d_in[6];
  const float* cb   = (const float*)d_in[7];
  const float* xpw  = (const float*)d_in[8];
  const float* dtw  = (const float*)d_in[9];
  const float* dtb  = (const float*)d_in[10];
  const float* alog = (const float*)d_in[11];
  const float* dpp  = (const float*)d_in[12];
  const float* outw = (const float*)d_in[13];
  const float* pw   = (const float*)d_in[14];
  const float* pb   = (const float*)d_in[15];
  float* out = (float*)d_out;

  float* ws   = (float*)d_ws;
  float* x    = ws;                  // 524288
  float* xzu  = ws + 524288;         // 2097152
  float* xdbl = ws + 2621440;        // 131072
  float* yout = ws + 2752512;        // 1048576
  float* xpart= ws + 3801088;        // 1048576
  u16* ub     = (u16*)(ws + 4849664);
  u16* xn_bf  = ub;                  // 1048576
  u16* u_bf   = ub + 1048576;        // 2097152
  u16* g_bf   = ub + 3145728;        // 2097152
  u16* yg_bf  = ub + 5242880;        // 2097152
  u16* x_bf   = ub + 7340032;        // 524288
  u16* wb     = ub + 7864320;        // 26738688 bf16 weights (in|out|xp|pj)
  u16* wb_in  = wb;                  // 16777216
  u16* wb_out = wb + 16777216;       // 8388608
  u16* wb_xp  = wb + 25165824;       // 1048576
  u16* wb_pj  = wb + 26214400;       // 524288

  dim3 blk(256);

  embed_k<<<MT*DM/256, blk, 0, stream>>>(ts, ew, eb, x);
  wcastall_k<<<13056, blk, 0, stream>>>(inw, outw, xpw, pw, wb);

  for (int i=0;i<NLAYER;i++){
    rmscomb_k<<<MT, blk, 0, stream>>>(x, i ? yout : nullptr, nw + i*DM,
        xn_bf, xn_bf + MT*DM);
    // in_proj: (1024x512)@(2048x512)^T; u-half -> xzu fp32, z-half -> silu bf16 g
    mfma_nt<64,128,1,4><<<dim3(16,16,2), blk, 0, stream>>>(
        xn_bf, DM, (long)MT*DM, wb_in + (long)i*2097152, DM, 1048576,
        nullptr, g_bf, xzu, 1024, (long)MT*1024, MT, 2048, DM);
    conv_silu_k<<<512, blk, 0, stream>>>(xzu, cw + (long)i*2*DI*4, cb + i*2*DI, u_bf);
    // xproj: (1024x1024)@(64x1024)^T split-K=8 -> xpart
    mfma_nt<64,64,8,0><<<dim3(1,16,16), blk, 0, stream>>>(
        u_bf, DI, (long)MT*DI, wb_xp + (long)i*131072, DI, 65536,
        nullptr, nullptr, xpart, 64, 0, MT, 64, DI);
    xreduce_k<<<512, blk, 0, stream>>>(xpart, xdbl);
    // scan: delta reg-prefetch, 2 barriers/chunk
    scan_k<<<dim3(64, BS, 2), blk, 0, stream>>>(u_bf, g_bf, xdbl,
        dtw + (long)i*2*DI*DTR, dtb + (long)i*2*DI,
        alog + (long)i*2*DI*16, dpp + i*2*DI, yg_bf);
    // out_proj: (1024x1024)@(512x1024)^T
    mfma_nt<64,64,1,0><<<dim3(8,16,2), blk, 0, stream>>>(
        yg_bf, DI, (long)MT*DI, wb_out + (long)i*1048576, DI, 524288,
        nullptr, nullptr, yout, DM, (long)MT*DM, MT, DM, DI);
  }
  combcast_k<<<MT*DM/4/256, blk, 0, stream>>>(x, yout, x_bf);
  // final proj + bias + scatter
  mfma_nt<64,64,1,2><<<dim3(16,16,1), blk, 0, stream>>>(
      x_bf, DM, 0, wb_pj, DM, 0, pb, nullptr, out, 1024, 0, MT, 1024, DM);
}

// Round 23
// 721.702 us; speedup vs baseline: 1.1755x; 1.1755x over previous
//
#include <hip/hip_runtime.h>
#include <hip/hip_bf16.h>

#define DM 512      // d_model
#define DI 1024     // d_inner
#define DSTATE 16
#define DTR 32      // dt_rank
#define NLAYER 8
#define BS 4
#define LL 256      // tokens per batch (F*NP)
#define MT 1024     // BS*LL total tokens
#define DPROJ 256
#define CL 32       // scan chunk length
#define NCH (LL/CL)

typedef unsigned short u16;
typedef unsigned int u32;
typedef __attribute__((ext_vector_type(8))) short short8;
typedef __attribute__((ext_vector_type(4))) float f32x4;

__device__ __forceinline__ float sigmoidf_(float x){ return 1.f/(1.f+__expf(-x)); }

// fp32 -> bf16 round-to-nearest-even (finite inputs)
__device__ __forceinline__ u16 f2bf(float f){
  unsigned u = __float_as_uint(f);
  u = (u + 0x7FFF + ((u>>16)&1)) >> 16;
  return (u16)u;
}
__device__ __forceinline__ float bf2f(u16 v){
  return __uint_as_float(((unsigned)v) << 16);
}

// VALU-pipe 16-lane sum via DPP row rotations
template<int CTRL>
__device__ __forceinline__ float dpp_ror_add(float x){
  int y = __builtin_amdgcn_update_dpp(0, __float_as_int(x), CTRL, 0xF, 0xF, false);
  return x + __int_as_float(y);
}
__device__ __forceinline__ float sum16_dpp(float x){
  x = dpp_ror_add<0x128>(x);
  x = dpp_ror_add<0x124>(x);
  x = dpp_ror_add<0x122>(x);
  x = dpp_ror_add<0x121>(x);
  return x;
}

// ---------------- patch embed
__global__ __launch_bounds__(256) void embed_k(const float* __restrict__ ts,
    const float* __restrict__ ew, const float* __restrict__ eb, float* __restrict__ x){
  int idx = blockIdx.x*256 + threadIdx.x;     // MT*DM
  int m = idx >> 9, d = idx & 511;
  int b = m >> 8, np_ = m & 255;
  const float* t0 = ts + b*1024 + np_*4;
  float acc = eb[d];
  #pragma unroll
  for (int p=0;p<4;p++) acc = fmaf(t0[p], ew[d*4+p], acc);
  x[idx] = acc;
}

// ---------------- cast ALL weights to bf16; 2 coalesced float4 streams/thread
#define WHALF 3342336
__global__ __launch_bounds__(256) void wcastall_k(
    const float* __restrict__ w_in, const float* __restrict__ w_out,
    const float* __restrict__ w_xp, const float* __restrict__ w_pj,
    u16* __restrict__ dst){
  int t = blockIdx.x*256 + threadIdx.x;   // WHALF threads
  #pragma unroll
  for (int hh=0; hh<2; ++hh){
    long e4 = ((long)t + (long)hh*WHALF)*4;
    const float* src; long o;
    if      (e4 < 16777216) { src = w_in;  o = e4; }
    else if (e4 < 25165824) { src = w_out; o = e4 - 16777216; }
    else if (e4 < 26214400) { src = w_xp;  o = e4 - 25165824; }
    else                    { src = w_pj;  o = e4 - 26214400; }
    float4 v = *(const float4*)(src + o);
    ushort4 r; r.x=f2bf(v.x); r.y=f2bf(v.y); r.z=f2bf(v.z); r.w=f2bf(v.w);
    *(ushort4*)(dst + e4) = r;
  }
}

// ---------------- fused (residual combine) + rmsnorm -> bf16 normal+flipped
__global__ __launch_bounds__(256) void rmscomb_k(float* __restrict__ x,
    const float* __restrict__ yout,   // nullptr for layer 0
    const float* __restrict__ nw, u16* __restrict__ xnbf, u16* __restrict__ xnfbf){
  int m = blockIdx.x, t = threadIdx.x;
  int b = m>>8, l = m&255, mf = (b<<8)+(255-l);
  float2 v = *(const float2*)&x[(long)m*DM + t*2];
  if (yout){
    float2 f = *(const float2*)&yout[(long)m*DM + t*2];
    float2 g = *(const float2*)&yout[(long)MT*DM + (long)mf*DM + t*2];
    v.x += f.x + g.x; v.y += f.y + g.y;
    *(float2*)&x[(long)m*DM + t*2] = v;
  }
  float ss = v.x*v.x + v.y*v.y;
  ss += __shfl_down(ss,32); ss += __shfl_down(ss,16); ss += __shfl_down(ss,8);
  ss += __shfl_down(ss,4);  ss += __shfl_down(ss,2);  ss += __shfl_down(ss,1);
  __shared__ float ps[4];
  if ((t&63)==0) ps[t>>6] = ss;
  __syncthreads();
  float tot = ps[0]+ps[1]+ps[2]+ps[3];
  float rs = rsqrtf(tot*(1.f/DM) + 1e-5f);
  ushort2 o; o.x = f2bf(v.x*rs*nw[t*2]); o.y = f2bf(v.y*rs*nw[t*2+1]);
  *(ushort2*)&xnbf [(long)m *DM + t*2] = o;
  *(ushort2*)&xnfbf[(long)mf*DM + t*2] = o;
}

// ---------------- final combine + cast to bf16
__global__ __launch_bounds__(256) void combcast_k(const float* __restrict__ x,
    const float* __restrict__ yout, u16* __restrict__ xbf){
  int idx = blockIdx.x*256 + threadIdx.x;   // MT*DM/4
  int m = idx >> 7, c4 = idx & 127;
  int b = m>>8, l = m&255, mf = (b<<8)+(255-l);
  float4 r = ((const float4*)x)[idx];
  float4 f = ((const float4*)yout)[idx];
  float4 g = ((const float4*)(yout + (long)MT*DM))[(long)mf*128 + c4];
  ushort4 o;
  o.x = f2bf(r.x + f.x + g.x); o.y = f2bf(r.y + f.y + g.y);
  o.z = f2bf(r.z + f.z + g.z); o.w = f2bf(r.w + f.w + g.w);
  ((ushort4*)xbf)[idx] = o;
}

// ---------------- bf16 MFMA GEMM: C = A @ W^T (both bf16, global_load_lds staging)
// SPLITK>1: z = dir*SPLITK+kc, fp32 partials at C + z*M*N.
// EPI: 0 plain | 2 final scatter+bias | 4 in_proj split: n<1024 -> fp32 C, else silu bf16 -> G
template<int BM,int BN,int SPLITK,int EPI>
__global__ __launch_bounds__(256) void mfma_nt(
    const u16* __restrict__ A, int lda, long sA,
    const u16* __restrict__ W, int ldw, long sW,
    const float* __restrict__ bias, u16* __restrict__ G,
    float* __restrict__ C, int ldc, long sC,
    int M, int N, int K)
{
  constexpr int WM = BM/2, WN = BN/2;
  constexpr int MI = WM/16, NI = WN/16;
  int z = blockIdx.z;
  int dir = z / SPLITK, kc = z % SPLITK;
  int Klen = K / SPLITK;
  int kbase = kc * Klen;
  A += (long)dir * sA;
  W += (long)dir * sW;
  if (SPLITK > 1) C += (long)z * M * N; else C += (long)dir * sC;
  if (EPI==4) G += (long)dir * (long)MT*DI;

  __shared__ u16 Al[BM*32];
  __shared__ u16 Wl[BN*32];
  int tid = threadIdx.x;
  int lane = tid & 63;
  int wave = tid >> 6;
  int wm0 = (wave>>1)*WM, wn0 = (wave&1)*WN;
  int m0 = blockIdx.y*BM, n0 = blockIdx.x*BN;
  int l16 = lane>>4, l15 = lane&15;

  f32x4 acc[MI][NI] = {};

  for (int k0=0; k0<Klen; k0+=32){
    #pragma unroll
    for (int it=0; it<BM*4/256; ++it){
      int ch = it*256 + tid;
      int row = ch % BM, kk = ch / BM;
      const u16* g = A + (long)(m0+row)*lda + kbase + k0 + kk*8;
      __builtin_amdgcn_global_load_lds(
          (const __attribute__((address_space(1))) void*)g,
          (__attribute__((address_space(3))) void*)(Al + ch*8), 16, 0, 0);
    }
    #pragma unroll
    for (int it=0; it<BN*4/256; ++it){
      int ch = it*256 + tid;
      int row = ch % BN, kk = ch / BN;
      const u16* g = W + (long)(n0+row)*ldw + kbase + k0 + kk*8;
      __builtin_amdgcn_global_load_lds(
          (const __attribute__((address_space(1))) void*)g,
          (__attribute__((address_space(3))) void*)(Wl + ch*8), 16, 0, 0);
    }
    __syncthreads();
    short8 a[MI], b[NI];
    #pragma unroll
    for (int i=0;i<MI;i++)
      a[i] = *(const short8*)&Al[(l16*BM + wm0 + i*16 + l15)*8];
    #pragma unroll
    for (int j=0;j<NI;j++)
      b[j] = *(const short8*)&Wl[(l16*BN + wn0 + j*16 + l15)*8];
    #pragma unroll
    for (int i=0;i<MI;i++)
      #pragma unroll
      for (int j=0;j<NI;j++)
        acc[i][j] = __builtin_amdgcn_mfma_f32_16x16x32_bf16(a[i], b[j], acc[i][j], 0,0,0);
    __syncthreads();
  }
  #pragma unroll
  for (int i=0;i<MI;i++){
    #pragma unroll
    for (int j=0;j<NI;j++){
      #pragma unroll
      for (int r=0;r<4;r++){
        int m = m0 + wm0 + i*16 + l16*4 + r;
        int n = n0 + wn0 + j*16 + l15;
        float v = acc[i][j][r];
        if (EPI==2){
          v += bias[n];
          int bb = m>>8, np_ = m&255, p = n>>8, dp = n&255;
          C[((long)(bb*1024 + np_*4 + p))*256 + dp] = v;
        } else if (EPI==4){
          if (n < 1024) C[(long)m*1024 + n] = v;
          else          G[(long)m*1024 + (n-1024)] = f2bf(v * sigmoidf_(v));
        } else {
          C[(long)m*ldc + n] = v;
        }
      }
    }
  }
}

// ---------------- split-K reduce for xproj
__global__ __launch_bounds__(256) void xreduce_k(const float* __restrict__ part,
    float* __restrict__ xdbl){
  int idx = blockIdx.x*256 + threadIdx.x;   // 131072
  int d = idx >> 16, off = idx & 65535;
  float s = 0.f;
  #pragma unroll
  for (int kc=0; kc<8; ++kc) s += part[((d*8+kc)<<16) + off];
  xdbl[idx] = s;
}

// ---------------- causal depthwise conv + bias + silu -> bf16 u (vectorized 4e x 4l)
__global__ __launch_bounds__(256) void conv_silu_k(const float* __restrict__ xzu,
    const float* __restrict__ cw, const float* __restrict__ cb,
    u16* __restrict__ ubf){
  int idx = blockIdx.x*256 + threadIdx.x;   // 131072
  int e = (idx & 255) * 4;
  int grp = idx >> 8;          // 512: dir(1) | b(2) | lg(6)
  int dir = grp >> 8;
  int b   = (grp >> 6) & 3;
  int l0  = (grp & 63) * 4;
  long dm0 = (long)dir*MT + b*LL + l0;
  const float* w = cw + ((long)dir*DI + e)*4;
  float4 w0 = *(const float4*)&w[0];
  float4 w1 = *(const float4*)&w[4];
  float4 w2 = *(const float4*)&w[8];
  float4 w3 = *(const float4*)&w[12];
  float4 bias = *(const float4*)&cb[dir*DI + e];
  const float* src = xzu + dm0*DI + e;
  float4 vb[7];
  #pragma unroll
  for (int j=0;j<7;j++){
    int l = l0 - 3 + j;
    if (l >= 0) vb[j] = *(const float4*)&src[(long)(j-3)*DI];
    else        vb[j] = make_float4(0.f,0.f,0.f,0.f);
  }
  #pragma unroll
  for (int j=0;j<4;j++){
    float4 acc = bias;
    acc.x = fmaf(w0.x, vb[j].x,   acc.x); acc.x = fmaf(w0.y, vb[j+1].x, acc.x);
    acc.x = fmaf(w0.z, vb[j+2].x, acc.x); acc.x = fmaf(w0.w, vb[j+3].x, acc.x);
    acc.y = fmaf(w1.x, vb[j].y,   acc.y); acc.y = fmaf(w1.y, vb[j+1].y, acc.y);
    acc.y = fmaf(w1.z, vb[j+2].y, acc.y); acc.y = fmaf(w1.w, vb[j+3].y, acc.y);
    acc.z = fmaf(w2.x, vb[j].z,   acc.z); acc.z = fmaf(w2.y, vb[j+1].z, acc.z);
    acc.z = fmaf(w2.z, vb[j+2].z, acc.z); acc.z = fmaf(w2.w, vb[j+3].z, acc.z);
    acc.w = fmaf(w3.x, vb[j].w,   acc.w); acc.w = fmaf(w3.y, vb[j+1].w, acc.w);
    acc.w = fmaf(w3.z, vb[j+2].w, acc.w); acc.w = fmaf(w3.w, vb[j+3].w, acc.w);
    float vx = acc.x * sigmoidf_(acc.x);
    float vy = acc.y * sigmoidf_(acc.y);
    float vz = acc.z * sigmoidf_(acc.z);
    float vw = acc.w * sigmoidf_(acc.w);
    ushort4 o; o.x=f2bf(vx); o.y=f2bf(vy); o.z=f2bf(vz); o.w=f2bf(vw);
    *(ushort4*)&ubf[(dm0+j)*DI + e] = o;
  }
}

// ---------------- selective scan: R21 structure, 2 barriers/chunk (no dreg prefetch)
__global__ __launch_bounds__(256) void scan_k(
    const u16* __restrict__ ubf, const u16* __restrict__ gbf,
    const float* __restrict__ xdbl, const float* __restrict__ dtw,
    const float* __restrict__ dtb, const float* __restrict__ A_log,
    const float* __restrict__ Dp, u16* __restrict__ ygbf)
{
  int t = threadIdx.x;
  int n = t & 15, el = t >> 4;
  int id = blockIdx.x + 64*blockIdx.y + 256*blockIdx.z;   // 0..511
  int xcd = id & 7, slot = id >> 3;
  int ec = xcd*8 + (slot & 7);
  int bd = slot >> 3;
  int b = bd & 3, dir = bd >> 2;

  int e0 = ec*16, e = e0 + el;
  float Av = -__expf(A_log[((long)dir*DI + e)*16 + n]);
  float Dv = Dp[dir*DI + e];
  long mbase = (long)dir*MT + b*LL;
  const u16* up_ = ubf + mbase*DI;
  const u16* gp_ = gbf + mbase*DI;
  const float* xd_ = xdbl + mbase*64;
  u16* yp_ = ygbf + mbase*DI;

  float wrow[32];
  {
    const float* wr = dtw + ((long)dir*DI + e0 + n)*32;
    #pragma unroll
    for (int r4=0;r4<8;r4++) *(float4*)&wrow[r4*4] = *(const float4*)&wr[r4*4];
  }
  float dtbv = dtb[dir*DI + e0 + n];

  __shared__ float sDU[2][16][68];   // [el][l*2 + {0:d,1:u}]
  __shared__ float sBC[2][16][68];   // [n][l*2 + {0:B,1:C}]
  __shared__ float sy [32][20];

  float4 xbc; ushort4 uvv;
  auto load_pre = [&](int c){
    long l0 = (long)c*CL;
    int row = t >> 3, c4 = (t & 7)*4;     // 32 rows x 8 float4 (cols 32..63)
    xbc = *(const float4*)&xd_[(l0 + row)*64 + 32 + c4];
    if (t < 128) uvv = *(const ushort4*)&up_[(l0 + (t>>2))*DI + e0 + (t&3)*4];
  };
  auto write_pre = [&](int buf){
    int row = t >> 3, c4 = (t & 7)*4;
    if (c4 < 16){
      int nb = c4;
      sBC[buf][nb  ][row*2] = xbc.x; sBC[buf][nb+1][row*2] = xbc.y;
      sBC[buf][nb+2][row*2] = xbc.z; sBC[buf][nb+3][row*2] = xbc.w;
    } else {
      int nb = c4 - 16;
      sBC[buf][nb  ][row*2+1] = xbc.x; sBC[buf][nb+1][row*2+1] = xbc.y;
      sBC[buf][nb+2][row*2+1] = xbc.z; sBC[buf][nb+3][row*2+1] = xbc.w;
    }
    if (t < 128){
      int l = t>>2, e4 = (t&3)*4;
      sDU[buf][e4  ][l*2+1] = bf2f(uvv.x);
      sDU[buf][e4+1][l*2+1] = bf2f(uvv.y);
      sDU[buf][e4+2][l*2+1] = bf2f(uvv.z);
      sDU[buf][e4+3][l*2+1] = bf2f(uvv.w);
    }
  };

  load_pre(0);
  write_pre(0);
  load_pre(1);
  __syncthreads();

  float h = 0.f;
  int lp = t >> 4;
  for (int c = 0; c < NCH; ++c){
    int cur = c & 1;
    // delta: thread computes at (l = lp + j*16, e = e0+n); reads xdbl rows from L2
    #pragma unroll
    for (int j=0;j<2;j++){
      int l = lp + j*16;
      const float* row = &xd_[((long)c*CL + l)*64];
      float acc = dtbv;
      #pragma unroll
      for (int r4=0;r4<8;r4++){
        float4 d4 = *(const float4*)&row[r4*4];
        acc = fmaf(d4.x, wrow[r4*4],   acc);
        acc = fmaf(d4.y, wrow[r4*4+1], acc);
        acc = fmaf(d4.z, wrow[r4*4+2], acc);
        acc = fmaf(d4.w, wrow[r4*4+3], acc);
      }
      acc = fmaxf(acc, 0.f) + __logf(1.f + __expf(-fabsf(acc)));
      sDU[cur][n][l*2] = acc;
    }
    ushort4 gv;
    if (t < 128) gv = *(const ushort4*)&gp_[((long)c*CL + (t>>2))*DI + e0 + (t&3)*4];
    __syncthreads();   // #1: d-slots + staged buffers visible

    const float* pDU = &sDU[cur][el][0];
    const float* pBC = &sBC[cur][n][0];
    float4 duv[16], bcv[16];
    #pragma unroll
    for (int l2=0; l2<16; ++l2){
      duv[l2] = *(const float4*)&pDU[l2*4];
      bcv[l2] = *(const float4*)&pBC[l2*4];
    }
    float dA[32], sv[32], cv[32], ud[32];
    #pragma unroll
    for (int l2=0; l2<16; ++l2){
      dA[2*l2]   = __expf(duv[l2].x*Av);
      sv[2*l2]   = duv[l2].x*duv[l2].y*bcv[l2].x;
      cv[2*l2]   = bcv[l2].y;
      ud[2*l2]   = duv[l2].y*Dv;
      dA[2*l2+1] = __expf(duv[l2].z*Av);
      sv[2*l2+1] = duv[l2].z*duv[l2].w*bcv[l2].z;
      cv[2*l2+1] = bcv[l2].w;
      ud[2*l2+1] = duv[l2].w*Dv;
    }
    #pragma unroll
    for (int l=0; l<32; ++l){
      h = fmaf(dA[l], h, sv[l]);
      sv[l] = h;
    }
    #pragma unroll
    for (int l=0; l<32; ++l) sv[l] = sum16_dpp(sv[l]*cv[l]);
    if (n==0){
      #pragma unroll
      for (int l=0; l<32; ++l) sy[l][el] = sv[l] + ud[l];
    }
    __syncthreads();   // #2: sy complete; buffers[cur] free
    if (c+1 < NCH){
      write_pre(cur^1);
      if (c+2 < NCH) load_pre(c+2);
    }
    if (t < 128){
      float4 y4 = *(const float4*)&sy[t>>2][(t&3)*4];
      ushort4 o;
      o.x = f2bf(y4.x * bf2f(gv.x)); o.y = f2bf(y4.y * bf2f(gv.y));
      o.z = f2bf(y4.z * bf2f(gv.z)); o.w = f2bf(y4.w * bf2f(gv.w));
      *(ushort4*)&yp_[((long)c*CL + (t>>2))*DI + e0 + (t&3)*4] = o;
    }
    // no 3rd barrier: next iteration's barrier #1 orders the sy/LDS hazards
  }
}

extern "C" void kernel_launch(void* const* d_in, const int* in_sizes, int n_in,
                              void* d_out, int out_size, void* d_ws, size_t ws_size,
                              hipStream_t stream){
  const float* ts   = (const float*)d_in[0];
  const float* ew   = (const float*)d_in[2];
  const float* eb   = (const float*)d_in[3];
  const float* nw   = (const float*)d_in[4];
  const float* inw  = (const float*)d_in[5];
  const float* cw   = (const float*)d_in[6];
  const float* cb   = (const float*)d_in[7];
  const float* xpw  = (const float*)d_in[8];
  const float* dtw  = (const float*)d_in[9];
  const float* dtb  = (const float*)d_in[10];
  const float* alog = (const float*)d_in[11];
  const float* dpp  = (const float*)d_in[12];
  const float* outw = (const float*)d_in[13];
  const float* pw   = (const float*)d_in[14];
  const float* pb   = (const float*)d_in[15];
  float* out = (float*)d_out;

  float* ws   = (float*)d_ws;
  float* x    = ws;                  // 524288
  float* xzu  = ws + 524288;         // 2097152
  float* xdbl = ws + 2621440;        // 131072
  float* yout = ws + 2752512;        // 1048576
  float* xpart= ws + 3801088;        // 1048576
  u16* ub     = (u16*)(ws + 4849664);
  u16* xn_bf  = ub;                  // 1048576
  u16* u_bf   = ub + 1048576;        // 2097152
  u16* g_bf   = ub + 3145728;        // 2097152
  u16* yg_bf  = ub + 5242880;        // 2097152
  u16* x_bf   = ub + 7340032;        // 524288
  u16* wb     = ub + 7864320;        // 26738688 bf16 weights (in|out|xp|pj)
  u16* wb_in  = wb;                  // 16777216
  u16* wb_out = wb + 16777216;       // 8388608
  u16* wb_xp  = wb + 25165824;       // 1048576
  u16* wb_pj  = wb + 26214400;       // 524288

  dim3 blk(256);

  embed_k<<<MT*DM/256, blk, 0, stream>>>(ts, ew, eb, x);
  wcastall_k<<<13056, blk, 0, stream>>>(inw, outw, xpw, pw, wb);

  for (int i=0;i<NLAYER;i++){
    rmscomb_k<<<MT, blk, 0, stream>>>(x, i ? yout : nullptr, nw + i*DM,
        xn_bf, xn_bf + MT*DM);
    // in_proj: (1024x512)@(2048x512)^T; u-half -> xzu fp32, z-half -> silu bf16 g
    mfma_nt<64,128,1,4><<<dim3(16,16,2), blk, 0, stream>>>(
        xn_bf, DM, (long)MT*DM, wb_in + (long)i*2097152, DM, 1048576,
        nullptr, g_bf, xzu, 1024, (long)MT*1024, MT, 2048, DM);
    conv_silu_k<<<512, blk, 0, stream>>>(xzu, cw + (long)i*2*DI*4, cb + i*2*DI, u_bf);
    // xproj: (1024x1024)@(64x1024)^T split-K=8 -> xpart
    mfma_nt<64,64,8,0><<<dim3(1,16,16), blk, 0, stream>>>(
        u_bf, DI, (long)MT*DI, wb_xp + (long)i*131072, DI, 65536,
        nullptr, nullptr, xpart, 64, 0, MT, 64, DI);
    xreduce_k<<<512, blk, 0, stream>>>(xpart, xdbl);
    // scan: 2 barriers/chunk
    scan_k<<<dim3(64, BS, 2), blk, 0, stream>>>(u_bf, g_bf, xdbl,
        dtw + (long)i*2*DI*DTR, dtb + (long)i*2*DI,
        alog + (long)i*2*DI*16, dpp + i*2*DI, yg_bf);
    // out_proj: (1024x1024)@(512x1024)^T
    mfma_nt<64,64,1,0><<<dim3(8,16,2), blk, 0, stream>>>(
        yg_bf, DI, (long)MT*DI, wb_out + (long)i*1048576, DI, 524288,
        nullptr, nullptr, yout, DM, (long)MT*DM, MT, DM, DI);
  }
  combcast_k<<<MT*DM/4/256, blk, 0, stream>>>(x, yout, x_bf);
  // final proj + bias + scatter
  mfma_nt<64,64,1,2><<<dim3(16,16,1), blk, 0, stream>>>(
      x_bf, DM, 0, wb_pj, DM, 0, pb, nullptr, out, 1024, 0, MT, 1024, DM);
}